// Round 2
// baseline (1527.057 us; speedup 1.0000x reference)
//
#include <hip/hip_runtime.h>
#include <hip/hip_bf16.h>

// Problem constants (MultiHeadAttention: B=2, S=4096, D=512, H=8, depth=64)
// All inputs/outputs are fp32 (reference dtype). Workspace: Q,K fp32; V,O bf16.
#define NH   8
#define DH   64
#define NB   2
#define SEQ  4096
#define DM   512
#define MR   (NB * SEQ)   // 8192 rows for the projection GEMMs

__device__ __forceinline__ float bf2f(unsigned short u) {
    union { unsigned int i; float f; } c;
    c.i = ((unsigned int)u) << 16;
    return c.f;
}

__device__ __forceinline__ unsigned short f2bf(float f) {
    union { float f; unsigned int u; } c;
    c.f = f;
    unsigned int r = c.u + 0x7FFF + ((c.u >> 16) & 1);
    return (unsigned short)(r >> 16);
}

// C[M,512] = X[M,512] @ W[512,512] + bias
// XMODE: 0 = X fp32, 1 = X bf16 (workspace)
// OMODE: 0 = fp32 head-split [B,H,S,64]; 1 = bf16 head-split; 2 = fp32 flat [M,512]
template<int XMODE, int OMODE>
__global__ __launch_bounds__(256) void gemm512(const void* __restrict__ Xv,
                                               const float* __restrict__ W,
                                               const float* __restrict__ bias,
                                               void* __restrict__ outv)
{
    // Transposed X tile so inner-loop reads are ds_read_b128.
    // Stride 68 floats = 272 B (16B-aligned rows; <=2-way read conflicts = free).
    __shared__ float XsT[64][68];  // [k][row]
    __shared__ float Ws [64][68];  // [k][col]

    const int tid = threadIdx.x;
    const int tx = tid & 15, ty = tid >> 4;
    const int row0 = blockIdx.x * 64;
    const int col0 = blockIdx.y * 64;

    float acc[4][4] = {};

    for (int k0 = 0; k0 < DM; k0 += 64) {
#pragma unroll
        for (int i = 0; i < 4; ++i) {
            const int r = i * 16 + ty;
            const int c = tx * 4;
            float x0, x1, x2, x3;
            if (XMODE == 0) {
                const float* X = (const float*)Xv;
                float4 u = *(const float4*)(X + (size_t)(row0 + r) * DM + k0 + c);
                x0 = u.x; x1 = u.y; x2 = u.z; x3 = u.w;
            } else {
                const unsigned short* X = (const unsigned short*)Xv;
                ushort4 u = *(const ushort4*)(X + (size_t)(row0 + r) * DM + k0 + c);
                x0 = bf2f(u.x); x1 = bf2f(u.y); x2 = bf2f(u.z); x3 = bf2f(u.w);
            }
            XsT[c + 0][r] = x0; XsT[c + 1][r] = x1;
            XsT[c + 2][r] = x2; XsT[c + 3][r] = x3;

            float4 w = *(const float4*)(W + (size_t)(k0 + r) * DM + col0 + c);
            Ws[r][c + 0] = w.x; Ws[r][c + 1] = w.y;
            Ws[r][c + 2] = w.z; Ws[r][c + 3] = w.w;
        }
        __syncthreads();

#pragma unroll 16
        for (int kk = 0; kk < 64; ++kk) {
            const float4 a4 = *(const float4*)&XsT[kk][ty * 4];
            const float4 b4 = *(const float4*)&Ws[kk][tx * 4];
            const float a[4]  = { a4.x, a4.y, a4.z, a4.w };
            const float bw[4] = { b4.x, b4.y, b4.z, b4.w };
#pragma unroll
            for (int i = 0; i < 4; ++i)
#pragma unroll
                for (int j = 0; j < 4; ++j)
                    acc[i][j] = fmaf(a[i], bw[j], acc[i][j]);
        }
        __syncthreads();
    }

    float bv[4];
#pragma unroll
    for (int j = 0; j < 4; ++j) bv[j] = bias[col0 + tx * 4 + j];

#pragma unroll
    for (int i = 0; i < 4; ++i) {
        const int row = row0 + ty * 4 + i;
        const float c0 = acc[i][0] + bv[0];
        const float c1 = acc[i][1] + bv[1];
        const float c2 = acc[i][2] + bv[2];
        const float c3 = acc[i][3] + bv[3];
        if (OMODE == 0) {
            float* out = (float*)outv;
            const int bb = row >> 12;          // row / SEQ
            const int s  = row & (SEQ - 1);
            // h == blockIdx.y because tile width (64) == DEPTH
            *(float4*)&out[(((size_t)bb * NH + blockIdx.y) * SEQ + s) * DH + tx * 4] =
                make_float4(c0, c1, c2, c3);
        } else if (OMODE == 1) {
            unsigned short* out = (unsigned short*)outv;
            const int bb = row >> 12;
            const int s  = row & (SEQ - 1);
            ushort4 val;
            val.x = f2bf(c0); val.y = f2bf(c1); val.z = f2bf(c2); val.w = f2bf(c3);
            *(ushort4*)&out[(((size_t)bb * NH + blockIdx.y) * SEQ + s) * DH + tx * 4] = val;
        } else {
            float* out = (float*)outv;
            *(float4*)&out[(size_t)row * DM + col0 + tx * 4] =
                make_float4(c0, c1, c2, c3);
        }
    }
}

// Flash attention. Q,K fp32 [B*H,S,64]; V bf16 [B*H,S,64]; mask fp32 [B,1,1,S];
// O bf16 [B,S,512]. grid = (S/64, B*H), block = 256.
// NOTE: reference does NOT scale by 1/sqrt(d).
__global__ __launch_bounds__(256) void flash_attn(
    const float* __restrict__ Q, const float* __restrict__ K,
    const unsigned short* __restrict__ V, const float* __restrict__ mask,
    unsigned short* __restrict__ O)
{
    __shared__ float QsT[64][68];  // [dim][q-row]
    __shared__ float KPs[64][68];  // K phase: [dim][key]; P phase: [key][q-row]
    __shared__ float Vs [64][68];  // [key][dim]

    const int tid = threadIdx.x;
    const int tx = tid & 15, ty = tid >> 4;
    const int bh = blockIdx.y;
    const int b  = bh >> 3;
    const int h  = bh & 7;
    const int q0 = blockIdx.x * 64;

    const float* Qh = Q + (size_t)bh * SEQ * DH;
    const float* Kh = K + (size_t)bh * SEQ * DH;
    const unsigned short* Vh = V + (size_t)bh * SEQ * DH;

#pragma unroll
    for (int i = 0; i < 4; ++i) {
        const int r = i * 16 + ty;
        const float4 u = *(const float4*)&Qh[(size_t)(q0 + r) * DH + tx * 4];
        QsT[tx * 4 + 0][r] = u.x; QsT[tx * 4 + 1][r] = u.y;
        QsT[tx * 4 + 2][r] = u.z; QsT[tx * 4 + 3][r] = u.w;
    }

    float m_r[4], l_r[4], o_acc[4][4];
#pragma unroll
    for (int i = 0; i < 4; ++i) {
        m_r[i] = -INFINITY; l_r[i] = 0.f;
#pragma unroll
        for (int j = 0; j < 4; ++j) o_acc[i][j] = 0.f;
    }

    for (int t0 = 0; t0 < SEQ; t0 += 64) {
#pragma unroll
        for (int i = 0; i < 4; ++i) {
            const int r = i * 16 + ty;
            const float4 kv = *(const float4*)&Kh[(size_t)(t0 + r) * DH + tx * 4];
            KPs[tx * 4 + 0][r] = kv.x; KPs[tx * 4 + 1][r] = kv.y;
            KPs[tx * 4 + 2][r] = kv.z; KPs[tx * 4 + 3][r] = kv.w;
            const ushort4 vv = *(const ushort4*)&Vh[(size_t)(t0 + r) * DH + tx * 4];
            Vs[r][tx * 4 + 0] = bf2f(vv.x); Vs[r][tx * 4 + 1] = bf2f(vv.y);
            Vs[r][tx * 4 + 2] = bf2f(vv.z); Vs[r][tx * 4 + 3] = bf2f(vv.w);
        }
        __syncthreads();

        // S-tile: rows q0+ty*4+i, cols (keys) t0+tx*4+j
        float sacc[4][4] = {};
#pragma unroll 16
        for (int kk = 0; kk < 64; ++kk) {
            const float4 a4 = *(const float4*)&QsT[kk][ty * 4];
            const float4 b4 = *(const float4*)&KPs[kk][tx * 4];
            const float a[4]  = { a4.x, a4.y, a4.z, a4.w };
            const float kw[4] = { b4.x, b4.y, b4.z, b4.w };
#pragma unroll
            for (int i = 0; i < 4; ++i)
#pragma unroll
                for (int j = 0; j < 4; ++j)
                    sacc[i][j] = fmaf(a[i], kw[j], sacc[i][j]);
        }

        // mask[b,0,0,key] * -1e9
        const float4 mu = *(const float4*)&mask[(size_t)b * SEQ + t0 + tx * 4];
        const float mv[4] = { mu.x * -1e9f, mu.y * -1e9f, mu.z * -1e9f, mu.w * -1e9f };
#pragma unroll
        for (int i = 0; i < 4; ++i)
#pragma unroll
            for (int j = 0; j < 4; ++j) sacc[i][j] += mv[j];

        // online softmax; each q-row is owned by 16 consecutive lanes (same ty)
        float p[4][4];
#pragma unroll
        for (int i = 0; i < 4; ++i) {
            float tmax = fmaxf(fmaxf(sacc[i][0], sacc[i][1]),
                               fmaxf(sacc[i][2], sacc[i][3]));
#pragma unroll
            for (int off = 1; off < 16; off <<= 1)
                tmax = fmaxf(tmax, __shfl_xor(tmax, off, 16));
            const float m_new = fmaxf(m_r[i], tmax);
            const float alpha = __expf(m_r[i] - m_new);  // first tile: exp(-inf)=0
            m_r[i] = m_new;
            float rsum = 0.f;
#pragma unroll
            for (int j = 0; j < 4; ++j) {
                p[i][j] = __expf(sacc[i][j] - m_new);
                rsum += p[i][j];
            }
#pragma unroll
            for (int off = 1; off < 16; off <<= 1)
                rsum += __shfl_xor(rsum, off, 16);
            l_r[i] = fmaf(l_r[i], alpha, rsum);
#pragma unroll
            for (int j = 0; j < 4; ++j) o_acc[i][j] *= alpha;
        }
        __syncthreads();  // everyone done reading K from KPs

        // stash P^T into KPs: [key][q-row]
#pragma unroll
        for (int j = 0; j < 4; ++j) {
            *(float4*)&KPs[tx * 4 + j][ty * 4] =
                make_float4(p[0][j], p[1][j], p[2][j], p[3][j]);
        }
        __syncthreads();  // P visible

        // O += P @ V : o_acc[i][j] over rows q0+ty*4+i, dims tx*4+j
#pragma unroll 16
        for (int t = 0; t < 64; ++t) {
            const float4 a4 = *(const float4*)&KPs[t][ty * 4];
            const float4 v4 = *(const float4*)&Vs[t][tx * 4];
            const float a[4]  = { a4.x, a4.y, a4.z, a4.w };
            const float vv[4] = { v4.x, v4.y, v4.z, v4.w };
#pragma unroll
            for (int i = 0; i < 4; ++i)
#pragma unroll
                for (int j = 0; j < 4; ++j)
                    o_acc[i][j] = fmaf(a[i], vv[j], o_acc[i][j]);
        }
        __syncthreads();  // done with KPs/Vs before next tile load
    }

    // write O[b, s, h*64 + d] bf16 (workspace)
#pragma unroll
    for (int i = 0; i < 4; ++i) {
        const int row = q0 + ty * 4 + i;
        const float inv = 1.0f / l_r[i];
        ushort4 o;
        o.x = f2bf(o_acc[i][0] * inv);
        o.y = f2bf(o_acc[i][1] * inv);
        o.z = f2bf(o_acc[i][2] * inv);
        o.w = f2bf(o_acc[i][3] * inv);
        *(ushort4*)&O[((size_t)b * SEQ + row) * DM + h * DH + tx * 4] = o;
    }
}

extern "C" void kernel_launch(void* const* d_in, const int* in_sizes, int n_in,
                              void* d_out, int out_size, void* d_ws, size_t ws_size,
                              hipStream_t stream) {
    // setup_inputs order: q,k,v,mask,wq,bq,wk,bk,wv,bv,wo,bo — all fp32
    const float* q    = (const float*)d_in[0];
    const float* k    = (const float*)d_in[1];
    const float* v    = (const float*)d_in[2];
    const float* mask = (const float*)d_in[3];
    const float* wq   = (const float*)d_in[4];
    const float* bq   = (const float*)d_in[5];
    const float* wk   = (const float*)d_in[6];
    const float* bk   = (const float*)d_in[7];
    const float* wv   = (const float*)d_in[8];
    const float* bv   = (const float*)d_in[9];
    const float* wo   = (const float*)d_in[10];
    const float* bo   = (const float*)d_in[11];

    // workspace (48 MiB): Q,K fp32 [B,H,S,64]; V bf16 [B,H,S,64]; O bf16 [B,S,512]
    float* Qws = (float*)d_ws;                                // 16 MiB
    float* Kws = Qws + (size_t)MR * DM;                       // 16 MiB
    unsigned short* Vws = (unsigned short*)(Kws + (size_t)MR * DM);  // 8 MiB
    unsigned short* Ows = Vws + (size_t)MR * DM;              // 8 MiB

    const dim3 gg(MR / 64, DM / 64);   // 128 x 8
    gemm512<0, 0><<<gg, 256, 0, stream>>>(q, wq, bq, Qws);
    gemm512<0, 0><<<gg, 256, 0, stream>>>(k, wk, bk, Kws);
    gemm512<0, 1><<<gg, 256, 0, stream>>>(v, wv, bv, Vws);

    flash_attn<<<dim3(SEQ / 64, NB * NH), 256, 0, stream>>>(Qws, Kws, Vws, mask, Ows);

    gemm512<1, 2><<<gg, 256, 0, stream>>>(Ows, wo, bo, d_out);
}

// Round 4
// 387.753 us; speedup vs baseline: 3.9382x; 3.9382x over previous
//
#include <hip/hip_runtime.h>
#include <hip/hip_bf16.h>

// MultiHeadAttention: B=2, S=4096, D=512, H=8, depth=64. fp32 in/out.
// All matmuls via mfma_f32_16x16x32_f16 (fp16: 11-bit mantissa — bf16 was
// not precise enough for the unscaled logits, absmax 0.114 > 0.086).
// Workspace: Q,K,V f16 [B,H,S,64], O f16 [B,S,512] (~34 MiB).
#define NH   8
#define DH   64
#define NB   2
#define SEQ  4096
#define DM   512
#define MR   (NB * SEQ)

using f16x8 = __attribute__((ext_vector_type(8))) _Float16;
using f32x4 = __attribute__((ext_vector_type(4))) float;
#define MFMA16(a, b, c) __builtin_amdgcn_mfma_f32_16x16x32_f16(a, b, c, 0, 0, 0)

// LDS row stride: 72 halves = 144 B (16B-aligned rows).
#define LSTR 72

// ---------------------------------------------------------------------------
// GEMM: C[M,512] = X[M,512] @ W[512,512] + bias, via f16 MFMA (fp32 accum).
// XMODE: 0 = X fp32 global input; 1 = X f16 workspace.
// OMODE: 0 = f16 head-split [B,H,S,64] (head == blockIdx.y, tile width 64);
//        1 = fp32 flat [M,512] (final output).
// grid (M/128, 512/64), block 256 (4 waves, wave w owns rows w*32..w*32+32).
// ---------------------------------------------------------------------------
template<int XMODE, int OMODE>
__global__ __launch_bounds__(256) void gemm_mfma(const void* __restrict__ Xv,
                                                 const float* __restrict__ W,
                                                 const float* __restrict__ bias,
                                                 void* __restrict__ outv)
{
    __shared__ _Float16 Xs[128 * LSTR];   // [row][k]
    __shared__ _Float16 WsT[64 * LSTR];   // [n][k], chunk-swizzled

    const int t = threadIdx.x;
    const int l = t & 63, w = t >> 6;
    const int m = l & 15, g = l >> 4;
    const int row0 = blockIdx.x * 128;
    const int col0 = blockIdx.y * 64;

    f32x4 acc[2][4] = {};

    for (int k0 = 0; k0 < DM; k0 += 64) {
        // ---- stage X tile (128x64) into Xs ----
        if (XMODE == 0) {
            const float* X = (const float*)Xv;
#pragma unroll
            for (int i = 0; i < 8; ++i) {
                const int r  = i * 16 + (t >> 4);
                const int c4 = (t & 15) * 4;
                float4 u = *(const float4*)(X + (size_t)(row0 + r) * DM + k0 + c4);
                _Float16 hh[4] = { (_Float16)u.x, (_Float16)u.y,
                                   (_Float16)u.z, (_Float16)u.w };
                *(uint2*)&Xs[r * LSTR + c4] = *(const uint2*)hh;
            }
        } else {
            const _Float16* X = (const _Float16*)Xv;
#pragma unroll
            for (int i = 0; i < 4; ++i) {
                const int r  = i * 32 + (t >> 3);
                const int c8 = (t & 7) * 8;
                *(uint4*)&Xs[r * LSTR + c8] =
                    *(const uint4*)(X + (size_t)(row0 + r) * DM + k0 + c8);
            }
        }
        // ---- stage W tile transposed (WsT[n][k]) with chunk swizzle ----
#pragma unroll
        for (int i = 0; i < 4; ++i) {
            const int k  = i * 16 + (t >> 4);
            const int n0 = (t & 15) * 4;
            float4 u = *(const float4*)(W + (size_t)(k0 + k) * DM + col0 + n0);
            float uu[4] = { u.x, u.y, u.z, u.w };
#pragma unroll
            for (int j = 0; j < 4; ++j) {
                const int n = n0 + j;
                const int chunk = (k >> 3) ^ ((n >> 3) & 7);
                WsT[n * LSTR + chunk * 8 + (k & 7)] = (_Float16)uu[j];
            }
        }
        __syncthreads();

        // ---- MFMA: 2 row-tiles x 4 col-tiles x 2 k-steps ----
#pragma unroll
        for (int kk = 0; kk < 2; ++kk) {
            f16x8 a0 = *(const f16x8*)&Xs[(w * 32 + m) * LSTR + kk * 32 + g * 8];
            f16x8 a1 = *(const f16x8*)&Xs[(w * 32 + 16 + m) * LSTR + kk * 32 + g * 8];
#pragma unroll
            for (int ct = 0; ct < 4; ++ct) {
                const int n = ct * 16 + m;
                f16x8 bf = *(const f16x8*)&WsT[n * LSTR + 8 * (((kk * 4 + g) ^ ((n >> 3) & 7)))];
                acc[0][ct] = MFMA16(a0, bf, acc[0][ct]);
                acc[1][ct] = MFMA16(a1, bf, acc[1][ct]);
            }
        }
        __syncthreads();
    }

    // ---- epilogue: bias + store (C layout: row = g*4+reg, col = ct*16+m) ----
    float bv[4];
#pragma unroll
    for (int ct = 0; ct < 4; ++ct) bv[ct] = bias[col0 + ct * 16 + m];

#pragma unroll
    for (int rt = 0; rt < 2; ++rt) {
#pragma unroll
        for (int reg = 0; reg < 4; ++reg) {
            const int row = row0 + w * 32 + rt * 16 + g * 4 + reg;
#pragma unroll
            for (int ct = 0; ct < 4; ++ct) {
                const float val = acc[rt][ct][reg] + bv[ct];
                if (OMODE == 0) {
                    const int bb = row >> 12;
                    const int s  = row & (SEQ - 1);
                    ((_Float16*)outv)[(((size_t)bb * NH + blockIdx.y) * SEQ + s) * DH
                                      + ct * 16 + m] = (_Float16)val;
                } else {
                    ((float*)outv)[(size_t)row * DM + col0 + ct * 16 + m] = val;
                }
            }
        }
    }
}

// ---------------------------------------------------------------------------
// Flash attention, f16 MFMA (fp32 accum/softmax). Q,K,V f16 [B*H,S,64];
// mask fp32 [B,1,1,S]; O f16 [B,S,512]. grid (S/128, B*H), block 256.
// NOTE: reference does NOT scale by 1/sqrt(d).
// ---------------------------------------------------------------------------
__global__ __launch_bounds__(256) void flash_mfma(
    const _Float16* __restrict__ Q, const _Float16* __restrict__ K,
    const _Float16* __restrict__ V, const float* __restrict__ mask,
    _Float16* __restrict__ O)
{
    __shared__ _Float16 Qs [128 * LSTR];  // [qrow][dim]
    __shared__ _Float16 Ks [64 * LSTR];   // [key][dim]
    __shared__ _Float16 VTs[64 * LSTR];   // [dim][key], chunk-swizzled
    __shared__ _Float16 Ps [128 * LSTR];  // [qrow][key], chunk-swizzled

    const int t = threadIdx.x;
    const int l = t & 63, w = t >> 6;
    const int m = l & 15, g = l >> 4;
    const int bh = blockIdx.y;
    const int b  = bh >> 3;
    const int h  = bh & 7;
    const int q0 = blockIdx.x * 128;

    const _Float16* Qh = Q + (size_t)bh * SEQ * DH;
    const _Float16* Kh = K + (size_t)bh * SEQ * DH;
    const _Float16* Vh = V + (size_t)bh * SEQ * DH;
    const float* maskb = mask + (size_t)b * SEQ;

    // load Q tile once
#pragma unroll
    for (int i = 0; i < 4; ++i) {
        const int r  = i * 32 + (t >> 3);
        const int c8 = (t & 7) * 8;
        *(uint4*)&Qs[r * LSTR + c8] = *(const uint4*)(Qh + (size_t)(q0 + r) * DH + c8);
    }

    float m_r[2][4], l_r[2][4];
    f32x4 oacc[2][4] = {};
#pragma unroll
    for (int rt = 0; rt < 2; ++rt)
#pragma unroll
        for (int reg = 0; reg < 4; ++reg) { m_r[rt][reg] = -INFINITY; l_r[rt][reg] = 0.f; }

    for (int t0 = 0; t0 < SEQ; t0 += 64) {
        // ---- stage K (natural) and V (transposed, swizzled) ----
#pragma unroll
        for (int i = 0; i < 2; ++i) {
            const int key = i * 32 + (t >> 3);
            const int d0  = (t & 7) * 8;
            *(uint4*)&Ks[key * LSTR + d0] =
                *(const uint4*)(Kh + (size_t)(t0 + key) * DH + d0);
            _Float16 vv[8];
            *(uint4*)vv = *(const uint4*)(Vh + (size_t)(t0 + key) * DH + d0);
#pragma unroll
            for (int j = 0; j < 8; ++j) {
                const int d = d0 + j;
                VTs[d * LSTR + 8 * ((key >> 3) ^ ((d >> 3) & 7)) + (key & 7)] = vv[j];
            }
        }
        __syncthreads();

        // ---- S = Q K^T (wave rows w*32..+32, keys 0..63 of tile) ----
        f32x4 sacc[2][4] = {};
#pragma unroll
        for (int kk = 0; kk < 2; ++kk) {
            f16x8 a0 = *(const f16x8*)&Qs[(w * 32 + m) * LSTR + kk * 32 + g * 8];
            f16x8 a1 = *(const f16x8*)&Qs[(w * 32 + 16 + m) * LSTR + kk * 32 + g * 8];
#pragma unroll
            for (int ct = 0; ct < 4; ++ct) {
                f16x8 bk = *(const f16x8*)&Ks[(ct * 16 + m) * LSTR + kk * 32 + g * 8];
                sacc[0][ct] = MFMA16(a0, bk, sacc[0][ct]);
                sacc[1][ct] = MFMA16(a1, bk, sacc[1][ct]);
            }
        }

        // ---- mask + online softmax (row = rt*16 + g*4 + reg, col = ct*16+m) ----
        float mv[4];
#pragma unroll
        for (int ct = 0; ct < 4; ++ct) mv[ct] = maskb[t0 + ct * 16 + m] * -1e9f;

#pragma unroll
        for (int rt = 0; rt < 2; ++rt) {
#pragma unroll
            for (int reg = 0; reg < 4; ++reg) {
                float s0 = sacc[rt][0][reg] + mv[0];
                float s1 = sacc[rt][1][reg] + mv[1];
                float s2 = sacc[rt][2][reg] + mv[2];
                float s3 = sacc[rt][3][reg] + mv[3];
                float rmax = fmaxf(fmaxf(s0, s1), fmaxf(s2, s3));
                rmax = fmaxf(rmax, __shfl_xor(rmax, 1));
                rmax = fmaxf(rmax, __shfl_xor(rmax, 2));
                rmax = fmaxf(rmax, __shfl_xor(rmax, 4));
                rmax = fmaxf(rmax, __shfl_xor(rmax, 8));
                const float mold = m_r[rt][reg];
                const float mnew = fmaxf(mold, rmax);
                const float alpha = __expf(mold - mnew);   // first tile: exp(-inf)=0
                m_r[rt][reg] = mnew;
                const float p0 = __expf(s0 - mnew);
                const float p1 = __expf(s1 - mnew);
                const float p2 = __expf(s2 - mnew);
                const float p3 = __expf(s3 - mnew);
                float rsum = p0 + p1 + p2 + p3;
                rsum += __shfl_xor(rsum, 1);
                rsum += __shfl_xor(rsum, 2);
                rsum += __shfl_xor(rsum, 4);
                rsum += __shfl_xor(rsum, 8);
                l_r[rt][reg] = l_r[rt][reg] * alpha + rsum;
#pragma unroll
                for (int nt = 0; nt < 4; ++nt) oacc[rt][nt][reg] *= alpha;

                // write P (f16) to Ps[row][key], chunk-swizzled by (row>>1)&7
                const int row  = w * 32 + rt * 16 + g * 4 + reg;
                const int swz  = (row >> 1) & 7;
                const int base = row * LSTR;
                const int mh   = m >> 3, ml = m & 7;
                Ps[base + 8 * ((0 + mh) ^ swz) + ml] = (_Float16)p0;
                Ps[base + 8 * ((2 + mh) ^ swz) + ml] = (_Float16)p1;
                Ps[base + 8 * ((4 + mh) ^ swz) + ml] = (_Float16)p2;
                Ps[base + 8 * ((6 + mh) ^ swz) + ml] = (_Float16)p3;
            }
        }
        // P is wave-local (rows w*32..+32 written and read by wave w only):
        // no __syncthreads needed before PV.

        // ---- O += P V ----
#pragma unroll
        for (int kk = 0; kk < 2; ++kk) {
            const int pswz = (m >> 1) & 7;
            f16x8 a0 = *(const f16x8*)&Ps[(w * 32 + m) * LSTR + 8 * ((kk * 4 + g) ^ pswz)];
            f16x8 a1 = *(const f16x8*)&Ps[(w * 32 + 16 + m) * LSTR + 8 * ((kk * 4 + g) ^ pswz)];
#pragma unroll
            for (int nt = 0; nt < 4; ++nt) {
                const int n = nt * 16 + m;
                f16x8 bv = *(const f16x8*)&VTs[n * LSTR + 8 * ((kk * 4 + g) ^ ((n >> 3) & 7))];
                oacc[0][nt] = MFMA16(a0, bv, oacc[0][nt]);
                oacc[1][nt] = MFMA16(a1, bv, oacc[1][nt]);
            }
        }
        __syncthreads();   // Ks/VTs consumed; safe to restage next tile
    }

    // ---- normalize + store O[b, s, h*64+dim] f16 ----
#pragma unroll
    for (int rt = 0; rt < 2; ++rt) {
#pragma unroll
        for (int reg = 0; reg < 4; ++reg) {
            const int row = q0 + w * 32 + rt * 16 + g * 4 + reg;
            const float inv = 1.0f / l_r[rt][reg];
#pragma unroll
            for (int nt = 0; nt < 4; ++nt) {
                O[((size_t)b * SEQ + row) * DM + h * DH + nt * 16 + m] =
                    (_Float16)(oacc[rt][nt][reg] * inv);
            }
        }
    }
}

extern "C" void kernel_launch(void* const* d_in, const int* in_sizes, int n_in,
                              void* d_out, int out_size, void* d_ws, size_t ws_size,
                              hipStream_t stream) {
    const float* q    = (const float*)d_in[0];
    const float* k    = (const float*)d_in[1];
    const float* v    = (const float*)d_in[2];
    const float* mask = (const float*)d_in[3];
    const float* wq   = (const float*)d_in[4];
    const float* bq   = (const float*)d_in[5];
    const float* wk   = (const float*)d_in[6];
    const float* bk   = (const float*)d_in[7];
    const float* wv   = (const float*)d_in[8];
    const float* bv   = (const float*)d_in[9];
    const float* wo   = (const float*)d_in[10];
    const float* bo   = (const float*)d_in[11];

    // workspace: Q,K,V f16 [B,H,S,64] (8 MiB each), O f16 [B,S,512] (8 MiB)
    _Float16* Qws = (_Float16*)d_ws;
    _Float16* Kws = Qws + (size_t)MR * DM;
    _Float16* Vws = Kws + (size_t)MR * DM;
    _Float16* Ows = Vws + (size_t)MR * DM;

    const dim3 gg(MR / 128, DM / 64);   // 64 x 8
    gemm_mfma<0, 0><<<gg, 256, 0, stream>>>(q, wq, bq, Qws);
    gemm_mfma<0, 0><<<gg, 256, 0, stream>>>(k, wk, bk, Kws);
    gemm_mfma<0, 0><<<gg, 256, 0, stream>>>(v, wv, bv, Vws);

    flash_mfma<<<dim3(SEQ / 128, NB * NH), 256, 0, stream>>>(Qws, Kws, Vws, mask, Ows);

    gemm_mfma<1, 1><<<gg, 256, 0, stream>>>(Ows, wo, bo, d_out);
}